// Round 5
// baseline (785.516 us; speedup 1.0000x reference)
//
#include <hip/hip_runtime.h>
#include <cstdint>
#include <cstddef>

typedef __fp16 half2v __attribute__((ext_vector_type(2)));

__device__ __forceinline__ int rdlane_i(int v, int lane) {
    return __builtin_amdgcn_readlane(v, lane);
}

template <int Q>
__device__ __forceinline__ float quad_bcast(float v) {
    return __int_as_float(__builtin_amdgcn_update_dpp(
        0, __float_as_int(v), Q * 0x55, 0xF, 0xF, true));
}

__device__ __forceinline__ half2v h2_from_int(int x) {
    union { int i; half2v h; } u; u.i = x; return u.h;
}
__device__ __forceinline__ int int_from_h2(half2v h) {
    union { int i; half2v h2; } u; u.h2 = h; return u.i;
}

// tanh via Pade[7/6] + exact output clamp (ratio >= 1 for |x| >= 5, monotone):
// tanh(x) ~= x(135135 + 17325u + 378u^2 + u^3) / (135135 + 62370u + 3150u^2 + 28u^3)
__device__ __forceinline__ float ptanh(float x) {
    float u = x * x;
    float p = u + 378.0f;
    p = fmaf(p, u, 17325.0f);
    p = fmaf(p, u, 135135.0f);
    p = p * x;
    float q = fmaf(28.0f, u, 3150.0f);
    q = fmaf(q, u, 62370.0f);
    q = fmaf(q, u, 135135.0f);
    float t = p * __builtin_amdgcn_rcpf(q);
    return __builtin_amdgcn_fmed3f(t, -1.0f, 1.0f);
}

// proj[d][v][s] = m(s) * (b[row] + W_ih[row,:] . emb[v,:]),  s = 4*j+g, row = g*15+j.
// m = 0.5 for sigmoid gates (sigma(z) = 0.5 + 0.5*tanh(z/2)), 1.0 for the tanh gate.
__global__ __launch_bounds__(256) void proj_kernel(
    const float* __restrict__ emb,
    const float* __restrict__ w_ih_f, const float* __restrict__ b_f,
    const float* __restrict__ w_ih_b, const float* __restrict__ b_b,
    float* __restrict__ proj, int V) {
    int gid = blockIdx.x * 256 + threadIdx.x;
    if (gid >= 2 * V * 64) return;
    int s = gid & 63;
    int v = (gid >> 6) % V;
    int d = gid / (V * 64);
    if (s >= 60) { proj[gid] = 0.0f; return; }
    int j = s >> 2, g = s & 3;
    int row = g * 15 + j;
    const float* w  = d ? w_ih_b : w_ih_f;
    const float* bv = d ? b_b   : b_f;
    float m = (g == 2) ? 1.0f : 0.5f;
    float acc = bv[row];
    #pragma unroll
    for (int k = 0; k < 15; ++k)
        acc = fmaf(emb[v * 15 + k], w[row * 15 + k], acc);
    proj[gid] = m * acc;
}

// One wave per (direction, sample). Lane = 4*j + g.
// Recurrent dot: h packed to f16 pairs (1 DPP + cvt_pkrtz), 8 readlanes, 8 v_dot2_f32_f16.
// Activations: Pade tanh (no transcendental exp), sigma folded as 0.5+0.5*tanh.
__global__ __launch_bounds__(64) void lstm_kernel(
    const int* __restrict__ data, const int* __restrict__ lengths,
    const float* __restrict__ proj,
    const float* __restrict__ h0, const float* __restrict__ c0,
    const float* __restrict__ w_hh_f, const float* __restrict__ w_hh_b,
    float* __restrict__ out, int T, int V) {
    const int lane = threadIdx.x;
    const int dir = blockIdx.x >> 6;
    const int b = blockIdx.x & 63;
    const int L = lengths[b];

    if (lane >= 60) return;

    const int j = lane >> 2;
    const int g = lane & 3;        // 0=i 1=f 2=g(tanh) 3=o
    const int row = g * 15 + j;

    const float* whh = dir ? w_hh_b : w_hh_f;
    const float mm = (g == 2) ? 1.0f : 0.5f;
    const float aa = (g == 2) ? 1.0f : 0.5f;
    const float ab = (g == 2) ? 0.0f : 0.5f;

    const bool gm0 = (g == 0), gm1 = (g == 1), gm2 = (g == 2), gm3 = (g == 3);

    // prescaled recurrent weights, packed to f16 pairs over k (k=15 pad -> 0)
    float whs[16];
    #pragma unroll
    for (int k = 0; k < 15; ++k) whs[k] = whh[row * 15 + k] * mm;
    whs[15] = 0.0f;
    half2v whp[8];
    #pragma unroll
    for (int a = 0; a < 8; ++a)
        whp[a] = __builtin_amdgcn_cvt_pkrtz(whs[2 * a], whs[2 * a + 1]);

    float h = h0[(dir * 64 + b) * 15 + j];   // replicated across quad
    float c = c0[(dir * 64 + b) * 15 + j];

    const int* drow = data + (size_t)b * T;
    const float* pj = proj + (size_t)dir * V * 64 + lane;
    const int sgn  = dir ? -1 : 1;
    const int base = dir ? (L - 1) : 0;

    float* wp = out + ((size_t)b * T + (size_t)(dir ? (L - 1 - g) : g)) * 45 + dir * 15 + j;
    float* outp = out + ((size_t)b * T) * 45 + dir * 15 + j;

    auto tok = [&](int t) -> int {
        int tt = t < L ? t : L - 1;
        return drow[base + sgn * tt];
    };

    auto step = [&](float xg) {
        // pack (h[l], h[l+4]) as f16x2; valid in lanes 0,8,...,56 (quads 2a,2a+1)
        int hni = __builtin_amdgcn_update_dpp(0, __float_as_int(h), 0x104, 0xF, 0xF, true); // row_shl:4
        half2v hpk = __builtin_amdgcn_cvt_pkrtz(h, __int_as_float(hni));
        int hv = int_from_h2(hpk);
        int k0 = rdlane_i(hv, 0),  k1 = rdlane_i(hv, 8),  k2 = rdlane_i(hv, 16), k3 = rdlane_i(hv, 24);
        int k4 = rdlane_i(hv, 32), k5 = rdlane_i(hv, 40), k6 = rdlane_i(hv, 48), k7 = rdlane_i(hv, 56);
        float a0 = xg, a1 = 0.f, a2 = 0.f, a3 = 0.f;
#if __has_builtin(__builtin_amdgcn_fdot2)
        a0 = __builtin_amdgcn_fdot2(whp[0], h2_from_int(k0), a0, false);
        a1 = __builtin_amdgcn_fdot2(whp[1], h2_from_int(k1), a1, false);
        a2 = __builtin_amdgcn_fdot2(whp[2], h2_from_int(k2), a2, false);
        a3 = __builtin_amdgcn_fdot2(whp[3], h2_from_int(k3), a3, false);
        a0 = __builtin_amdgcn_fdot2(whp[4], h2_from_int(k4), a0, false);
        a1 = __builtin_amdgcn_fdot2(whp[5], h2_from_int(k5), a1, false);
        a2 = __builtin_amdgcn_fdot2(whp[6], h2_from_int(k6), a2, false);
        a3 = __builtin_amdgcn_fdot2(whp[7], h2_from_int(k7), a3, false);
#else
        #pragma unroll
        for (int a = 0; a < 8; ++a) {
            int kk = (a==0)?k0:(a==1)?k1:(a==2)?k2:(a==3)?k3:(a==4)?k4:(a==5)?k5:(a==6)?k6:k7;
            half2v hh = h2_from_int(kk);
            float lo = (float)hh.x, hi = (float)hh.y;
            float* acc = (a & 3) == 0 ? &a0 : (a & 3) == 1 ? &a1 : (a & 3) == 2 ? &a2 : &a3;
            *acc = fmaf(lo, whs[2 * a], *acc);
            *acc = fmaf(hi, whs[2 * a + 1], *acc);
        }
#endif
        float z = (a0 + a1) + (a2 + a3);
        float r = fmaf(aa, ptanh(z), ab);     // sigmoid (i,f,o) or tanh (g)
        float vi = quad_bcast<0>(r);
        float vf = quad_bcast<1>(r);
        float vg = quad_bcast<2>(r);
        float vo = quad_bcast<3>(r);
        c = fmaf(vf, c, vi * vg);
        h = vo * ptanh(c);                    // replicated in quad
    };

    float xA[8], xB[8];
    int ta[8], tb[8];

    #pragma unroll
    for (int u = 0; u < 8; ++u) ta[u] = tok(u);
    #pragma unroll
    for (int u = 0; u < 8; ++u) xA[u] = pj[(size_t)ta[u] * 64];
    #pragma unroll
    for (int u = 0; u < 8; ++u) ta[u] = tok(8 + u);
    #pragma unroll
    for (int u = 0; u < 8; ++u) xB[u] = pj[(size_t)ta[u] * 64];
    #pragma unroll
    for (int u = 0; u < 8; ++u) ta[u] = tok(16 + u);
    #pragma unroll
    for (int u = 0; u < 8; ++u) tb[u] = tok(24 + u);

    auto halfrun = [&](float (&xb)[8], int (&tkb)[8], int th) {
        float hc = h;
        step(xb[0]); hc = gm0 ? h : hc;
        step(xb[1]); hc = gm1 ? h : hc;
        step(xb[2]); hc = gm2 ? h : hc;
        step(xb[3]); hc = gm3 ? h : hc;
        __builtin_nontemporal_store(hc, wp + (ptrdiff_t)sgn * th * 45);
        step(xb[4]); hc = gm0 ? h : hc;
        step(xb[5]); hc = gm1 ? h : hc;
        step(xb[6]); hc = gm2 ? h : hc;
        step(xb[7]); hc = gm3 ? h : hc;
        __builtin_nontemporal_store(hc, wp + (ptrdiff_t)sgn * (th + 4) * 45);
        #pragma unroll
        for (int u = 0; u < 8; ++u) xb[u] = pj[(size_t)tkb[u] * 64];
        #pragma unroll
        for (int u = 0; u < 8; ++u) tkb[u] = tok(th + 32 + u);
    };

    int t = 0;
    for (; t + 16 <= L; t += 16) {
        halfrun(xA, ta, t);
        halfrun(xB, tb, t + 8);
    }
    #pragma unroll 1
    for (int u = 0; u < 8 && t < L; ++u, ++t) {
        step(xA[u]);
        outp[(size_t)(base + sgn * t) * 45] = h;
    }
    #pragma unroll 1
    for (int u = 0; u < 8 && t < L; ++u, ++t) {
        step(xB[u]);
        outp[(size_t)(base + sgn * t) * 45] = h;
    }
}

// Epilogue: in-place linear 30 -> 45 per (b,t) row; rows t >= L get just lin_b.
__global__ __launch_bounds__(256) void linear_kernel(
    const int* __restrict__ lengths,
    const float* __restrict__ lin_w, const float* __restrict__ lin_b,
    float* out, int T) {
    __shared__ float Ws[45 * 30];
    __shared__ float Bs[45];
    for (int i = threadIdx.x; i < 45 * 30; i += 256) Ws[i] = lin_w[i];
    if (threadIdx.x < 45) Bs[threadIdx.x] = lin_b[threadIdx.x];
    __syncthreads();
    const int b = blockIdx.y;
    const int t = blockIdx.x * 256 + threadIdx.x;
    if (t >= T) return;
    const int L = lengths[b];
    float* row = out + ((size_t)b * T + t) * 45;
    float y[45];
    if (t < L) {
        float x[30];
        #pragma unroll
        for (int k = 0; k < 30; ++k) x[k] = row[k];
        #pragma unroll
        for (int o = 0; o < 45; ++o) {
            float acc = Bs[o];
            #pragma unroll
            for (int k = 0; k < 30; ++k) acc = fmaf(x[k], Ws[o * 30 + k], acc);
            y[o] = acc;
        }
    } else {
        #pragma unroll
        for (int o = 0; o < 45; ++o) y[o] = Bs[o];
    }
    #pragma unroll
    for (int o = 0; o < 45; ++o) row[o] = y[o];
}

extern "C" void kernel_launch(void* const* d_in, const int* in_sizes, int n_in,
                              void* d_out, int out_size, void* d_ws, size_t ws_size,
                              hipStream_t stream) {
    const int* data      = (const int*)d_in[0];
    const int* lengths   = (const int*)d_in[2];
    const float* emb     = (const float*)d_in[3];
    const float* h0      = (const float*)d_in[4];
    const float* c0      = (const float*)d_in[5];
    const float* w_ih_f  = (const float*)d_in[6];
    const float* w_hh_f  = (const float*)d_in[7];
    const float* b_f     = (const float*)d_in[8];
    const float* w_ih_b  = (const float*)d_in[9];
    const float* w_hh_b  = (const float*)d_in[10];
    const float* b_b     = (const float*)d_in[11];
    const float* lin_w   = (const float*)d_in[12];
    const float* lin_b   = (const float*)d_in[13];
    float* out = (float*)d_out;

    const int T = in_sizes[0] / 64;
    const int V = in_sizes[3] / 15;
    float* proj = (float*)d_ws;   // 2*V*64 floats = 25.6 MB

    hipLaunchKernelGGL(proj_kernel, dim3((2 * V * 64 + 255) / 256), dim3(256), 0, stream,
                       emb, w_ih_f, b_f, w_ih_b, b_b, proj, V);
    hipLaunchKernelGGL(lstm_kernel, dim3(128), dim3(64), 0, stream,
                       data, lengths, proj, h0, c0, w_hh_f, w_hh_b, out, T, V);
    hipLaunchKernelGGL(linear_kernel, dim3((T + 255) / 256, 64), dim3(256), 0, stream,
                       lengths, lin_w, lin_b, out, T);
}

// Round 6
// 767.337 us; speedup vs baseline: 1.0237x; 1.0237x over previous
//
#include <hip/hip_runtime.h>
#include <cstdint>
#include <cstddef>

__device__ __forceinline__ float rdlane(float v, int lane) {
    return __int_as_float(__builtin_amdgcn_readlane(__float_as_int(v), lane));
}

template <int Q>
__device__ __forceinline__ float quad_bcast(float v) {
    return __int_as_float(__builtin_amdgcn_update_dpp(
        0, __float_as_int(v), Q * 0x55, 0xF, 0xF, true));
}

// tanh via Pade[7/6] + exact output clamp (ratio >= 1 for |x| >= 5, monotone):
// tanh(x) ~= x(135135 + 17325u + 378u^2 + u^3) / (135135 + 62370u + 3150u^2 + 28u^3)
__device__ __forceinline__ float ptanh(float x) {
    float u = x * x;
    float p = u + 378.0f;
    p = fmaf(p, u, 17325.0f);
    p = fmaf(p, u, 135135.0f);
    p = p * x;
    float q = fmaf(28.0f, u, 3150.0f);
    q = fmaf(q, u, 62370.0f);
    q = fmaf(q, u, 135135.0f);
    float t = p * __builtin_amdgcn_rcpf(q);
    return __builtin_amdgcn_fmed3f(t, -1.0f, 1.0f);
}

// proj[d][v][s] = m(s) * (b[row] + W_ih[row,:] . emb[v,:]),  s = 4*j+g, row = g*15+j.
// m = 0.5 for sigmoid gates (sigma(z) = 0.5 + 0.5*tanh(z/2)), 1.0 for the tanh gate.
__global__ __launch_bounds__(256) void proj_kernel(
    const float* __restrict__ emb,
    const float* __restrict__ w_ih_f, const float* __restrict__ b_f,
    const float* __restrict__ w_ih_b, const float* __restrict__ b_b,
    float* __restrict__ proj, int V) {
    int gid = blockIdx.x * 256 + threadIdx.x;
    if (gid >= 2 * V * 64) return;
    int s = gid & 63;
    int v = (gid >> 6) % V;
    int d = gid / (V * 64);
    if (s >= 60) { proj[gid] = 0.0f; return; }
    int j = s >> 2, g = s & 3;
    int row = g * 15 + j;
    const float* w  = d ? w_ih_b : w_ih_f;
    const float* bv = d ? b_b   : b_f;
    float m = (g == 2) ? 1.0f : 0.5f;
    float acc = bv[row];
    #pragma unroll
    for (int k = 0; k < 15; ++k)
        acc = fmaf(emb[v * 15 + k], w[row * 15 + k], acc);
    proj[gid] = m * acc;
}

// One wave per (direction, sample). Lane = 4*j + g.
// Dot: 15x f32 v_readlane + 15 f32 FMA (R3-proven). Activations: Pade tanh
// (rcp only — no exp), sigma folded as (p+q)/(2q) with med3 clamp.
__global__ __launch_bounds__(64) void lstm_kernel(
    const int* __restrict__ data, const int* __restrict__ lengths,
    const float* __restrict__ proj,
    const float* __restrict__ h0, const float* __restrict__ c0,
    const float* __restrict__ w_hh_f, const float* __restrict__ w_hh_b,
    float* __restrict__ out, int T, int V) {
    const int lane = threadIdx.x;
    const int dir = blockIdx.x >> 6;
    const int b = blockIdx.x & 63;
    const int L = lengths[b];

    if (lane >= 60) return;

    const int j = lane >> 2;
    const int g = lane & 3;        // 0=i 1=f 2=g(tanh) 3=o
    const int row = g * 15 + j;

    const float* whh = dir ? w_hh_b : w_hh_f;
    const float mm = (g == 2) ? 1.0f : 0.5f;   // z/2 prescale for sigmoid gates
    const float rlo = (g == 2) ? -1.0f : 0.0f; // clamp lower bound per gate

    const bool gm0 = (g == 0), gm1 = (g == 1), gm2 = (g == 2), gm3 = (g == 3);

    float wh[15];
    #pragma unroll
    for (int k = 0; k < 15; ++k) wh[k] = whh[row * 15 + k] * mm;

    float h = h0[(dir * 64 + b) * 15 + j];   // replicated across quad
    float c = c0[(dir * 64 + b) * 15 + j];

    const int* drow = data + (size_t)b * T;
    const float* pj = proj + (size_t)dir * V * 64 + lane;
    const int sgn  = dir ? -1 : 1;
    const int base = dir ? (L - 1) : 0;

    float* wp = out + ((size_t)b * T + (size_t)(dir ? (L - 1 - g) : g)) * 45 + dir * 15 + j;
    float* outp = out + ((size_t)b * T) * 45 + dir * 15 + j;

    auto tok = [&](int t) -> int {
        int tt = t < L ? t : L - 1;
        return drow[base + sgn * tt];
    };

    auto step = [&](float xg) {
        float hk0 = rdlane(h, 0),  hk1 = rdlane(h, 4),  hk2 = rdlane(h, 8);
        float hk3 = rdlane(h, 12), hk4 = rdlane(h, 16), hk5 = rdlane(h, 20);
        float hk6 = rdlane(h, 24), hk7 = rdlane(h, 28), hk8 = rdlane(h, 32);
        float hk9 = rdlane(h, 36), hk10 = rdlane(h, 40), hk11 = rdlane(h, 44);
        float hk12 = rdlane(h, 48), hk13 = rdlane(h, 52), hk14 = rdlane(h, 56);
        float a0 = xg, a1 = 0.f, a2 = 0.f, a3 = 0.f;
        a0 = fmaf(hk0,  wh[0],  a0);  a1 = fmaf(hk1,  wh[1],  a1);
        a2 = fmaf(hk2,  wh[2],  a2);  a3 = fmaf(hk3,  wh[3],  a3);
        a0 = fmaf(hk4,  wh[4],  a0);  a1 = fmaf(hk5,  wh[5],  a1);
        a2 = fmaf(hk6,  wh[6],  a2);  a3 = fmaf(hk7,  wh[7],  a3);
        a0 = fmaf(hk8,  wh[8],  a0);  a1 = fmaf(hk9,  wh[9],  a1);
        a2 = fmaf(hk10, wh[10], a2);  a3 = fmaf(hk11, wh[11], a3);
        a0 = fmaf(hk12, wh[12], a0);  a1 = fmaf(hk13, wh[13], a1);
        a2 = fmaf(hk14, wh[14], a2);
        float z = (a0 + a1) + (a2 + a3);
        // activation: tanh(z) for g-gate, 0.5+0.5*tanh(z) for sigmoid gates
        // (z already halved via weight prescale). r = n/q, n = p (tanh) or (p+q)/2.
        float u = z * z;
        float p = u + 378.0f;
        p = fmaf(p, u, 17325.0f);
        p = fmaf(p, u, 135135.0f);
        p = p * z;
        float q = fmaf(28.0f, u, 3150.0f);
        q = fmaf(q, u, 62370.0f);
        q = fmaf(q, u, 135135.0f);
        float n = gm2 ? p : 0.5f * (p + q);   // off critical path (rcp in flight)
        float r = n * __builtin_amdgcn_rcpf(q);
        r = __builtin_amdgcn_fmed3f(r, rlo, 1.0f);
        float vf = quad_bcast<1>(r);          // f first: it's on the c critical path
        float vi = quad_bcast<0>(r);
        float vg = quad_bcast<2>(r);
        float vo = quad_bcast<3>(r);
        c = fmaf(vf, c, vi * vg);
        h = vo * ptanh(c);                    // replicated in quad
    };

    float xA[8], xB[8];
    int ta[8], tb[8];

    #pragma unroll
    for (int u = 0; u < 8; ++u) ta[u] = tok(u);
    #pragma unroll
    for (int u = 0; u < 8; ++u) xA[u] = pj[(size_t)ta[u] * 64];
    #pragma unroll
    for (int u = 0; u < 8; ++u) ta[u] = tok(8 + u);
    #pragma unroll
    for (int u = 0; u < 8; ++u) xB[u] = pj[(size_t)ta[u] * 64];
    #pragma unroll
    for (int u = 0; u < 8; ++u) ta[u] = tok(16 + u);
    #pragma unroll
    for (int u = 0; u < 8; ++u) tb[u] = tok(24 + u);

    auto halfrun = [&](float (&xb)[8], int (&tkb)[8], int th) {
        float hc = h;
        step(xb[0]); hc = gm0 ? h : hc;
        step(xb[1]); hc = gm1 ? h : hc;
        step(xb[2]); hc = gm2 ? h : hc;
        step(xb[3]); hc = gm3 ? h : hc;
        __builtin_nontemporal_store(hc, wp + (ptrdiff_t)sgn * th * 45);
        step(xb[4]); hc = gm0 ? h : hc;
        step(xb[5]); hc = gm1 ? h : hc;
        step(xb[6]); hc = gm2 ? h : hc;
        step(xb[7]); hc = gm3 ? h : hc;
        __builtin_nontemporal_store(hc, wp + (ptrdiff_t)sgn * (th + 4) * 45);
        #pragma unroll
        for (int u = 0; u < 8; ++u) xb[u] = pj[(size_t)tkb[u] * 64];
        #pragma unroll
        for (int u = 0; u < 8; ++u) tkb[u] = tok(th + 32 + u);
    };

    int t = 0;
    for (; t + 16 <= L; t += 16) {
        halfrun(xA, ta, t);
        halfrun(xB, tb, t + 8);
    }
    #pragma unroll 1
    for (int u = 0; u < 8 && t < L; ++u, ++t) {
        step(xA[u]);
        outp[(size_t)(base + sgn * t) * 45] = h;
    }
    #pragma unroll 1
    for (int u = 0; u < 8 && t < L; ++u, ++t) {
        step(xB[u]);
        outp[(size_t)(base + sgn * t) * 45] = h;
    }
}

// Epilogue: in-place linear 30 -> 45 per (b,t) row; rows t >= L get just lin_b.
__global__ __launch_bounds__(256) void linear_kernel(
    const int* __restrict__ lengths,
    const float* __restrict__ lin_w, const float* __restrict__ lin_b,
    float* out, int T) {
    __shared__ float Ws[45 * 30];
    __shared__ float Bs[45];
    for (int i = threadIdx.x; i < 45 * 30; i += 256) Ws[i] = lin_w[i];
    if (threadIdx.x < 45) Bs[threadIdx.x] = lin_b[threadIdx.x];
    __syncthreads();
    const int b = blockIdx.y;
    const int t = blockIdx.x * 256 + threadIdx.x;
    if (t >= T) return;
    const int L = lengths[b];
    float* row = out + ((size_t)b * T + t) * 45;
    float y[45];
    if (t < L) {
        float x[30];
        #pragma unroll
        for (int k = 0; k < 30; ++k) x[k] = row[k];
        #pragma unroll
        for (int o = 0; o < 45; ++o) {
            float acc = Bs[o];
            #pragma unroll
            for (int k = 0; k < 30; ++k) acc = fmaf(x[k], Ws[o * 30 + k], acc);
            y[o] = acc;
        }
    } else {
        #pragma unroll
        for (int o = 0; o < 45; ++o) y[o] = Bs[o];
    }
    #pragma unroll
    for (int o = 0; o < 45; ++o) row[o] = y[o];
}

extern "C" void kernel_launch(void* const* d_in, const int* in_sizes, int n_in,
                              void* d_out, int out_size, void* d_ws, size_t ws_size,
                              hipStream_t stream) {
    const int* data      = (const int*)d_in[0];
    const int* lengths   = (const int*)d_in[2];
    const float* emb     = (const float*)d_in[3];
    const float* h0      = (const float*)d_in[4];
    const float* c0      = (const float*)d_in[5];
    const float* w_ih_f  = (const float*)d_in[6];
    const float* w_hh_f  = (const float*)d_in[7];
    const float* b_f     = (const float*)d_in[8];
    const float* w_ih_b  = (const float*)d_in[9];
    const float* w_hh_b  = (const float*)d_in[10];
    const float* b_b     = (const float*)d_in[11];
    const float* lin_w   = (const float*)d_in[12];
    const float* lin_b   = (const float*)d_in[13];
    float* out = (float*)d_out;

    const int T = in_sizes[0] / 64;
    const int V = in_sizes[3] / 15;
    float* proj = (float*)d_ws;   // 2*V*64 floats = 25.6 MB

    hipLaunchKernelGGL(proj_kernel, dim3((2 * V * 64 + 255) / 256), dim3(256), 0, stream,
                       emb, w_ih_f, b_f, w_ih_b, b_b, proj, V);
    hipLaunchKernelGGL(lstm_kernel, dim3(128), dim3(64), 0, stream,
                       data, lengths, proj, h0, c0, w_hh_f, w_hh_b, out, T, V);
    hipLaunchKernelGGL(linear_kernel, dim3((T + 255) / 256, 64), dim3(256), 0, stream,
                       lengths, lin_w, lin_b, out, T);
}

// Round 7
// 706.432 us; speedup vs baseline: 1.1119x; 1.0862x over previous
//
#include <hip/hip_runtime.h>
#include <cstdint>
#include <cstddef>

#define LOG2E 1.442695040888963f

__device__ __forceinline__ float rdlane(float v, int lane) {
    return __int_as_float(__builtin_amdgcn_readlane(__float_as_int(v), lane));
}

template <int Q>
__device__ __forceinline__ float quad_bcast(float v) {
    // quad_perm broadcast of lane Q within each quad of 4 lanes
    return __int_as_float(__builtin_amdgcn_update_dpp(
        0, __float_as_int(v), Q * 0x55, 0xF, 0xF, true));
}

// proj[d][v][s] = m(s) * (b[row] + W_ih[row,:] . emb[v,:]),  s = 4*j+g, row = g*15+j.
// m = -log2e for sigmoid gates (w=rcp(1+exp2(z~)) = sigma(z)), -2log2e for the
// tanh gate (w=rcp(1+exp2(z~)) -> tanh(z)=2w-1).
__global__ __launch_bounds__(256) void proj_kernel(
    const float* __restrict__ emb,
    const float* __restrict__ w_ih_f, const float* __restrict__ b_f,
    const float* __restrict__ w_ih_b, const float* __restrict__ b_b,
    float* __restrict__ proj, int V) {
    int gid = blockIdx.x * 256 + threadIdx.x;
    if (gid >= 2 * V * 64) return;
    int s = gid & 63;
    int v = (gid >> 6) % V;
    int d = gid / (V * 64);
    if (s >= 60) { proj[gid] = 0.0f; return; }
    int j = s >> 2, g = s & 3;
    int row = g * 15 + j;
    const float* w  = d ? w_ih_b : w_ih_f;
    const float* bv = d ? b_b   : b_f;
    float m = (g == 2) ? (-2.0f * LOG2E) : (-LOG2E);
    float acc = bv[row];
    #pragma unroll
    for (int k = 0; k < 15; ++k)
        acc = fmaf(emb[v * 15 + k], w[row * 15 + k], acc);
    proj[gid] = m * acc;
}

// One wave per (direction, sample). Lane = 4*j + g (g: 0=i 1=f 2=g 3=o).
// Chain-minimized step: z tail-fma; raw-w broadcast; pre-scaled cell C=-2log2e*c
// (exp2(C) direct); fused h = fma(2wo, wc, -wo).
__global__ __launch_bounds__(64) void lstm_kernel(
    const int* __restrict__ data, const int* __restrict__ lengths,
    const float* __restrict__ proj,
    const float* __restrict__ h0, const float* __restrict__ c0,
    const float* __restrict__ w_hh_f, const float* __restrict__ w_hh_b,
    float* __restrict__ out, int T, int V) {
    const int lane = threadIdx.x;
    const int dir = blockIdx.x >> 6;
    const int b = blockIdx.x & 63;
    const int L = lengths[b];

    if (lane >= 60) return;

    const int j = lane >> 2;
    const int g = lane & 3;
    const int row = g * 15 + j;
    const float K = -2.0f * LOG2E;

    const float* whh = dir ? w_hh_b : w_hh_f;
    const float mm = (g == 2) ? K : (-LOG2E);   // gate prescale folded into U

    const bool gm0 = (g == 0), gm1 = (g == 1), gm2 = (g == 2), gm3 = (g == 3);

    float wh[15];
    #pragma unroll
    for (int k = 0; k < 15; ++k) wh[k] = whh[row * 15 + k] * mm;

    float h = h0[(dir * 64 + b) * 15 + j];        // replicated across quad
    float C = K * c0[(dir * 64 + b) * 15 + j];    // pre-scaled cell state

    const int* drow = data + (size_t)b * T;
    const float* pj = proj + (size_t)dir * V * 64 + lane;
    const int sgn  = dir ? -1 : 1;
    const int base = dir ? (L - 1) : 0;

    float* wp = out + ((size_t)b * T + (size_t)(dir ? (L - 1 - g) : g)) * 45 + dir * 15 + j;
    float* outp = out + ((size_t)b * T) * 45 + dir * 15 + j;

    auto tok = [&](int t) -> int {
        int tt = t < L ? t : L - 1;
        return drow[base + sgn * tt];
    };

    auto step = [&](float xg) {
        float hk0 = rdlane(h, 0),  hk1 = rdlane(h, 4),  hk2 = rdlane(h, 8);
        float hk3 = rdlane(h, 12), hk4 = rdlane(h, 16), hk5 = rdlane(h, 20);
        float hk6 = rdlane(h, 24), hk7 = rdlane(h, 28), hk8 = rdlane(h, 32);
        float hk9 = rdlane(h, 36), hk10 = rdlane(h, 40), hk11 = rdlane(h, 44);
        float hk12 = rdlane(h, 48), hk13 = rdlane(h, 52), hk14 = rdlane(h, 56);
        // 14 FMAs into 4 accumulators + combine during the readlane window;
        // the LAST readlane feeds the single tail fma -> 1 chain op after window.
        float a0 = xg, a1 = 0.f, a2 = 0.f, a3 = 0.f;
        a0 = fmaf(hk0,  wh[0],  a0);  a1 = fmaf(hk1,  wh[1],  a1);
        a2 = fmaf(hk2,  wh[2],  a2);  a3 = fmaf(hk3,  wh[3],  a3);
        a0 = fmaf(hk4,  wh[4],  a0);  a1 = fmaf(hk5,  wh[5],  a1);
        a2 = fmaf(hk6,  wh[6],  a2);  a3 = fmaf(hk7,  wh[7],  a3);
        a0 = fmaf(hk8,  wh[8],  a0);  a1 = fmaf(hk9,  wh[9],  a1);
        a2 = fmaf(hk10, wh[10], a2);  a3 = fmaf(hk11, wh[11], a3);
        a0 = fmaf(hk12, wh[12], a0);  a1 = fmaf(hk13, wh[13], a1);
        float s = (a0 + a1) + (a2 + a3);
        float z = fmaf(hk14, wh[14], s);
        // w = rcp(1 + exp2(z~)): sigma for i/f/o lanes; (tanh+1)/2 form for g lane
        float w = __builtin_amdgcn_rcpf(1.0f + __builtin_amdgcn_exp2f(z));
        float wf = quad_bcast<1>(w);          // f first: on the C critical path
        float wi = quad_bcast<0>(w);
        float wg = quad_bcast<2>(w);
        float wo = quad_bcast<3>(w);
        float tg = fmaf(2.0f, wg, -1.0f);     // tanh(z_g)
        float ai = K * wi;                    // K*sigma(z_i)   (parallel with tg)
        C = fmaf(wf, C, ai * tg);             // C = -2log2e * c
        float wc = __builtin_amdgcn_rcpf(1.0f + __builtin_amdgcn_exp2f(C));
        float p2 = wo + wo;                   // off-path while exp2/rcp in flight
        h = fmaf(p2, wc, -wo);                // vo * tanh(c), replicated in quad
    };

    float xA[8], xB[8];
    int ta[8], tb[8];

    #pragma unroll
    for (int u = 0; u < 8; ++u) ta[u] = tok(u);
    #pragma unroll
    for (int u = 0; u < 8; ++u) xA[u] = pj[(size_t)ta[u] * 64];
    #pragma unroll
    for (int u = 0; u < 8; ++u) ta[u] = tok(8 + u);
    #pragma unroll
    for (int u = 0; u < 8; ++u) xB[u] = pj[(size_t)ta[u] * 64];
    #pragma unroll
    for (int u = 0; u < 8; ++u) ta[u] = tok(16 + u);
    #pragma unroll
    for (int u = 0; u < 8; ++u) tb[u] = tok(24 + u);

    auto halfrun = [&](float (&xb)[8], int (&tkb)[8], int th) {
        float hc = h;
        step(xb[0]); hc = gm0 ? h : hc;
        step(xb[1]); hc = gm1 ? h : hc;
        step(xb[2]); hc = gm2 ? h : hc;
        step(xb[3]); hc = gm3 ? h : hc;
        __builtin_nontemporal_store(hc, wp + (ptrdiff_t)sgn * th * 45);
        step(xb[4]); hc = gm0 ? h : hc;
        step(xb[5]); hc = gm1 ? h : hc;
        step(xb[6]); hc = gm2 ? h : hc;
        step(xb[7]); hc = gm3 ? h : hc;
        __builtin_nontemporal_store(hc, wp + (ptrdiff_t)sgn * (th + 4) * 45);
        #pragma unroll
        for (int u = 0; u < 8; ++u) xb[u] = pj[(size_t)tkb[u] * 64];
        #pragma unroll
        for (int u = 0; u < 8; ++u) tkb[u] = tok(th + 32 + u);
    };

    int t = 0;
    for (; t + 16 <= L; t += 16) {
        halfrun(xA, ta, t);
        halfrun(xB, tb, t + 8);
    }
    #pragma unroll 1
    for (int u = 0; u < 8 && t < L; ++u, ++t) {
        step(xA[u]);
        outp[(size_t)(base + sgn * t) * 45] = h;
    }
    #pragma unroll 1
    for (int u = 0; u < 8 && t < L; ++u, ++t) {
        step(xB[u]);
        outp[(size_t)(base + sgn * t) * 45] = h;
    }
}

// Epilogue: in-place linear 30 -> 45 per (b,t) row; rows t >= L get just lin_b.
__global__ __launch_bounds__(256) void linear_kernel(
    const int* __restrict__ lengths,
    const float* __restrict__ lin_w, const float* __restrict__ lin_b,
    float* out, int T) {
    __shared__ float Ws[45 * 30];
    __shared__ float Bs[45];
    for (int i = threadIdx.x; i < 45 * 30; i += 256) Ws[i] = lin_w[i];
    if (threadIdx.x < 45) Bs[threadIdx.x] = lin_b[threadIdx.x];
    __syncthreads();
    const int b = blockIdx.y;
    const int t = blockIdx.x * 256 + threadIdx.x;
    if (t >= T) return;
    const int L = lengths[b];
    float* row = out + ((size_t)b * T + t) * 45;
    float y[45];
    if (t < L) {
        float x[30];
        #pragma unroll
        for (int k = 0; k < 30; ++k) x[k] = row[k];
        #pragma unroll
        for (int o = 0; o < 45; ++o) {
            float acc = Bs[o];
            #pragma unroll
            for (int k = 0; k < 30; ++k) acc = fmaf(x[k], Ws[o * 30 + k], acc);
            y[o] = acc;
        }
    } else {
        #pragma unroll
        for (int o = 0; o < 45; ++o) y[o] = Bs[o];
    }
    #pragma unroll
    for (int o = 0; o < 45; ++o) row[o] = y[o];
}

extern "C" void kernel_launch(void* const* d_in, const int* in_sizes, int n_in,
                              void* d_out, int out_size, void* d_ws, size_t ws_size,
                              hipStream_t stream) {
    const int* data      = (const int*)d_in[0];
    const int* lengths   = (const int*)d_in[2];
    const float* emb     = (const float*)d_in[3];
    const float* h0      = (const float*)d_in[4];
    const float* c0      = (const float*)d_in[5];
    const float* w_ih_f  = (const float*)d_in[6];
    const float* w_hh_f  = (const float*)d_in[7];
    const float* b_f     = (const float*)d_in[8];
    const float* w_ih_b  = (const float*)d_in[9];
    const float* w_hh_b  = (const float*)d_in[10];
    const float* b_b     = (const float*)d_in[11];
    const float* lin_w   = (const float*)d_in[12];
    const float* lin_b   = (const float*)d_in[13];
    float* out = (float*)d_out;

    const int T = in_sizes[0] / 64;
    const int V = in_sizes[3] / 15;
    float* proj = (float*)d_ws;   // 2*V*64 floats = 25.6 MB

    hipLaunchKernelGGL(proj_kernel, dim3((2 * V * 64 + 255) / 256), dim3(256), 0, stream,
                       emb, w_ih_f, b_f, w_ih_b, b_b, proj, V);
    hipLaunchKernelGGL(lstm_kernel, dim3(128), dim3(64), 0, stream,
                       data, lengths, proj, h0, c0, w_hh_f, w_hh_b, out, T, V);
    hipLaunchKernelGGL(linear_kernel, dim3((T + 255) / 256, 64), dim3(256), 0, stream,
                       lengths, lin_w, lin_b, out, T);
}